// Round 3
// baseline (927.101 us; speedup 1.0000x reference)
//
#include <hip/hip_runtime.h>
#include <hip/hip_bf16.h>
#include <math.h>

#define N_ATOMS 200000
#define M_NBR 12
#define F_DIM 64
#define NBR_FEA 41
#define ORIG_F 92
#define B_CRYS 2000
#define APB 100
#define SH_DIM 9
#define NCONV 3
#define HFEA 128
#define EDGES (N_ATOMS * M_NBR)   // 2,400,000

typedef __attribute__((ext_vector_type(8))) short short8;   // 8 bf16 = 4 VGPRs (MFMA A/B frag)
typedef __attribute__((ext_vector_type(4))) float floatx4;  // MFMA C/D frag

// 16B struct with natural float alignment (4B) — row bases are only 4B-aligned
struct f4u { float x, y, z, w; };

__device__ __forceinline__ unsigned short f2bf(float f) {
    __hip_bfloat16 h = __float2bfloat16(f);   // RN
    return *reinterpret_cast<unsigned short*>(&h);
}
__device__ __forceinline__ float bf2f(unsigned int u) {
    unsigned int x = u << 16;
    union { unsigned int i; float f; } c; c.i = x; return c.f;
}
__device__ __forceinline__ unsigned int pk2(float lo, float hi) {
    return (unsigned int)f2bf(lo) | ((unsigned int)f2bf(hi) << 16);
}
__device__ __forceinline__ float softplus_f(float x) {
    return fmaxf(x, 0.0f) + __logf(1.0f + __expf(-fabsf(x)));
}

// MFMA convention used throughout (verified by rounds 1-2 passing):
//   mfma(X, Y, C): both operand frags use t = lane&15, k = (lane>>4)*8+j
//   (+32 per extra K-frag).  D[row in X.t][col in Y.t]; C/D: col = lane&15,
//   row = (lane>>4)*4 + reg.

// ---------------------------------------------------------------------------
// k_prep: pack all constant weights into exact per-lane MFMA fragment layouts.
//  wpak  : Wr1^T * log2e as first-operand frags (filter computes H*log2e).
//  b1pk  : br1 * log2e in C/D layout.   w2pk: Wr2[:, 0] * ln2 in C/D layout.
//  wtpak : Wtp as frags  [(((l*64+lane)*4+nt)*2+s)*8+j] = Wtp[l][k][n],
//          n = nt*16+(lane&15), k = s*32+(lane>>4)*8+j.
//  wepak : W_emb as first-operand frags [(lane*12 + nt*3 + s)*8 + j],
//          n = nt*16+(lane&15), k = s*32+(lane>>4)*8+j (0 if k>=92).
//  bepk  : b_emb in C/D-row layout [(lane*4+nt)*4+reg] = b_emb[nt*16+quad*4+reg]
// ---------------------------------------------------------------------------
__global__ __launch_bounds__(256) void k_prep(
    const float* __restrict__ Wr1, const float* __restrict__ br1,
    const float* __restrict__ Wr2, const float* __restrict__ Wtp,
    const float* __restrict__ W_emb, const float* __restrict__ b_emb,
    unsigned short* __restrict__ wpak, float* __restrict__ w2pk,
    float* __restrict__ b1pk, unsigned short* __restrict__ wtpak,
    unsigned short* __restrict__ wepak, float* __restrict__ bepk)
{
    const float LOG2E = 1.4426950408889634f;
    const float LN2   = 0.69314718055994531f;
    int t = threadIdx.x;
    for (int i = t; i < 64 * 18 * 8; i += 256) {
        int lane = i / 144;
        int rem  = i - lane * 144;
        int fid  = rem >> 3;
        int j    = rem & 7;
        int l  = fid / 6;
        int rf = fid - l * 6;
        int nt = rf >> 1;
        int s  = rf & 1;
        int n = nt * 16 + (lane & 15);
        int k = s * 32 + (lane >> 4) * 8 + j;
        unsigned short v = 0;
        if (n < NBR_FEA && k < NBR_FEA)
            v = f2bf(Wr1[(l * NBR_FEA + k) * NBR_FEA + n] * LOG2E);
        wpak[i] = v;
    }
    for (int i = t; i < 3 * 64 * 3 * 4; i += 256) {
        int reg = i & 3;
        int q   = i >> 2;
        int nt  = q % 3;
        int q2  = q / 3;
        int lane = q2 & 63;
        int l    = q2 >> 6;
        int n = nt * 16 + (lane >> 4) * 4 + reg;
        float b = 0.f, w = 0.f;
        if (n < NBR_FEA) {
            b = br1[l * NBR_FEA + n] * LOG2E;
            w = Wr2[(l * NBR_FEA + n) * SH_DIM] * LN2;
        }
        b1pk[i] = b;
        w2pk[i] = w;
    }
    for (int i = t; i < 3 * 64 * 64; i += 256) {
        int j = i & 7;
        int q = i >> 3;
        int s = q & 1;  q >>= 1;
        int nt = q & 3; q >>= 2;
        int lane = q & 63;
        int l    = q >> 6;
        int k = s * 32 + (lane >> 4) * 8 + j;
        int n = nt * 16 + (lane & 15);
        wtpak[i] = f2bf(Wtp[(l * F_DIM + k) * F_DIM + n]);
    }
    for (int i = t; i < 64 * 12 * 8; i += 256) {
        int j = i & 7;
        int q = i >> 3;            // lane*12 + nt*3 + s
        int s = q % 3;
        int q2 = q / 3;
        int nt = q2 & 3;
        int lane = q2 >> 2;
        int n = nt * 16 + (lane & 15);
        int k = s * 32 + (lane >> 4) * 8 + j;
        wepak[i] = (k < ORIG_F) ? f2bf(W_emb[k * F_DIM + n]) : (unsigned short)0;
    }
    for (int i = t; i < 64 * 4 * 4; i += 256) {
        int reg = i & 3;
        int q = i >> 2;
        int nt = q & 3;
        int lane = q >> 2;
        bepk[i] = b_emb[nt * 16 + (lane >> 4) * 4 + reg];
    }
}

// ---------------------------------------------------------------------------
// Embed v2 (MFMA): X^T-tile = W_emb^T(64x96) . A^T(96x16), per wave one
// 16-atom tile, 4 n-tiles.  Atom rows loaded scattered fp32->bf16 (no reuse,
// no LDS).  Bias folded into C-init.  D rows = features -> per (nt) the 4
// acc regs are 4 consecutive features = one 8B store.
// ---------------------------------------------------------------------------
__global__ __launch_bounds__(256) void k_embed(
    const float* __restrict__ atom_fea, const unsigned short* __restrict__ wepak,
    const float* __restrict__ bepk, unsigned short* __restrict__ x)
{
    int tid  = threadIdx.x;
    int lane = tid & 63;
    int wv   = tid >> 6;
    int sub  = lane & 15;
    int quad = lane >> 4;
    long arow = (long)blockIdx.x * 64 + wv * 16 + sub;
    const float* ap = atom_fea + arow * ORIG_F;

    short8 bfrg[3];
    #pragma unroll
    for (int s = 0; s < 3; ++s) {
        int ko = s * 32 + quad * 8;            // k offset; K padded 92->96
        short8 f = {0,0,0,0,0,0,0,0};
        f4u a = *(const f4u*)(ap + ko);        // k ko..ko+3 always < 92
        f[0] = (short)f2bf(a.x); f[1] = (short)f2bf(a.y);
        f[2] = (short)f2bf(a.z); f[3] = (short)f2bf(a.w);
        if (s < 2 || quad < 3) {               // k ko+4..ko+7 valid except s2,q3
            f4u b = *(const f4u*)(ap + ko + 4);
            f[4] = (short)f2bf(b.x); f[5] = (short)f2bf(b.y);
            f[6] = (short)f2bf(b.z); f[7] = (short)f2bf(b.w);
        }
        bfrg[s] = f;
    }

    const unsigned short* wb = wepak + lane * 96;   // 192B/lane, 16B-aligned
    floatx4 acc[4];
    #pragma unroll
    for (int nt = 0; nt < 4; ++nt)
        acc[nt] = *(const floatx4*)&bepk[(lane * 4 + nt) * 4];
    #pragma unroll
    for (int s = 0; s < 3; ++s)
        #pragma unroll
        for (int nt = 0; nt < 4; ++nt)
            acc[nt] = __builtin_amdgcn_mfma_f32_16x16x32_bf16(
                *(const short8*)(wb + (nt * 3 + s) * 8), bfrg[s], acc[nt], 0, 0, 0);

    #pragma unroll
    for (int nt = 0; nt < 4; ++nt) {
        uint2 o = { pk2(acc[nt][0], acc[nt][1]), pk2(acc[nt][2], acc[nt][3]) };
        *(uint2*)&x[arow * F_DIM + nt * 16 + quad * 4] = o;
    }
}

// ---------------------------------------------------------------------------
// Edge filter v4: operand-swapped MFMA  D = (W1^T*log2e) . E^T  = H*log2e.
// softplus(H)*w2 = (max(acc,0) + log2(1+exp2(-|acc|))) * (w2*ln2):
// 5 VALU + 2 trans per element, no per-element mul, w2l regs freed.
// ---------------------------------------------------------------------------
__global__ __launch_bounds__(256) void k_filter(
    const float* __restrict__ nbr_fea,
    const unsigned short* __restrict__ wpak,
    const float* __restrict__ w2pk, const float* __restrict__ b1pk,
    const float* __restrict__ br2, float* __restrict__ W0)
{
    int tid  = threadIdx.x;
    int lane = tid & 63;
    int wv   = tid >> 6;
    int sub  = lane & 15;      // edge index within 16-tile (D col)
    int quad = lane >> 4;      // k-chunk on load side / n-quad on D side
    long ebase = (long)blockIdx.x * 256;

    // ---- E^T fragments: 64 rows per wave, cols partitioned over (s,quad)
    short8 efr[4][2];
    #pragma unroll
    for (int mt = 0; mt < 4; ++mt) {
        long r = ebase + wv * 64 + mt * 16 + sub;
        const float* rowp = nbr_fea + r * NBR_FEA;
        f4u a = *(const f4u*)(rowp + quad * 8);
        f4u b = *(const f4u*)(rowp + quad * 8 + 4);
        short8 f0;
        f0[0] = (short)f2bf(a.x); f0[1] = (short)f2bf(a.y);
        f0[2] = (short)f2bf(a.z); f0[3] = (short)f2bf(a.w);
        f0[4] = (short)f2bf(b.x); f0[5] = (short)f2bf(b.y);
        f0[6] = (short)f2bf(b.z); f0[7] = (short)f2bf(b.w);
        efr[mt][0] = f0;
        short8 f1 = {0, 0, 0, 0, 0, 0, 0, 0};
        if (quad == 0) {
            f4u c = *(const f4u*)(rowp + 32);
            f4u d = *(const f4u*)(rowp + 36);
            f1[0] = (short)f2bf(c.x); f1[1] = (short)f2bf(c.y);
            f1[2] = (short)f2bf(c.z); f1[3] = (short)f2bf(c.w);
            f1[4] = (short)f2bf(d.x); f1[5] = (short)f2bf(d.y);
            f1[6] = (short)f2bf(d.z); f1[7] = (short)f2bf(d.w);
        } else if (quad == 1) {
            f1[0] = (short)f2bf(rowp[40]);   // col 40; 41..47 are K-pad
        }
        efr[mt][1] = f1;
    }

    const unsigned short* abase = wpak + lane * 144;   // 288 B/lane, 16B-aligned

    #pragma unroll
    for (int l = 0; l < NCONV; ++l) {
        short8 wfr[3][2];
        #pragma unroll
        for (int nt = 0; nt < 3; ++nt)
            #pragma unroll
            for (int s = 0; s < 2; ++s)
                wfr[nt][s] = *(const short8*)(abase + ((l * 3 + nt) * 2 + s) * 8);

        floatx4 b1v[3], w2v[3];
        #pragma unroll
        for (int nt = 0; nt < 3; ++nt) {
            b1v[nt] = *(const floatx4*)&b1pk[((l * 64 + lane) * 3 + nt) * 4];
            w2v[nt] = *(const floatx4*)&w2pk[((l * 64 + lane) * 3 + nt) * 4];
        }

        floatx4 acc[3][4];
        #pragma unroll
        for (int nt = 0; nt < 3; ++nt)
            #pragma unroll
            for (int mt = 0; mt < 4; ++mt)
                acc[nt][mt] = b1v[nt];          // C-init = b1*log2e

        #pragma unroll
        for (int s = 0; s < 2; ++s)
            #pragma unroll
            for (int nt = 0; nt < 3; ++nt)
                #pragma unroll
                for (int mt = 0; mt < 4; ++mt)
                    acc[nt][mt] = __builtin_amdgcn_mfma_f32_16x16x32_bf16(
                        wfr[nt][s], efr[mt][s], acc[nt][mt], 0, 0, 0);

        float r2b = br2[l * SH_DIM];
        #pragma unroll
        for (int mt = 0; mt < 4; ++mt) {
            float t = 0.f;
            #pragma unroll
            for (int nt = 0; nt < 3; ++nt)
                #pragma unroll
                for (int reg = 0; reg < 4; ++reg) {
                    float xv = acc[nt][mt][reg];          // H * log2e
                    float e  = exp2f(-fabsf(xv));
                    float lg = __log2f(1.0f + e);
                    t = fmaf(fmaxf(xv, 0.f) + lg, w2v[nt][reg], t);
                }
            t += __shfl_xor(t, 16);
            t += __shfl_xor(t, 32);
            if (quad == 0)
                W0[(long)l * EDGES + ebase + wv * 64 + mt * 16 + sub] = t + r2b;
        }
    }
}

// ---------------------------------------------------------------------------
// Conv v3: idx/W0 staged in LDS (kills the global idx->gather dep chain and
// 24 lane-uniform VMEM/thread); gather 8 lanes/atom 16B; g bf16 in swizzled
// LDS; TP via operand-swapped MFMA -> D rows = features -> 2x 8B stores.
// ---------------------------------------------------------------------------
__global__ __launch_bounds__(256) void k_conv(
    const unsigned short* __restrict__ x_in, const int* __restrict__ nbr_idx,
    const float* __restrict__ W0, const unsigned short* __restrict__ wtp,
    unsigned short* __restrict__ x_out)
{
    __shared__ int   sIdx[32 * M_NBR];                         // 1536 B
    __shared__ float sW  [32 * M_NBR];                         // 1536 B
    __shared__ __align__(16) unsigned short gl[32 * F_DIM];    // 4 KB, swizzled
    int tid  = threadIdx.x;
    int lane = tid & 63;
    int wv   = tid >> 6;
    int aw   = lane >> 3;            // atom within wave 0..7
    int oct  = lane & 7;             // 16B chunk of the 128B feature row
    const float cscale = 0.28209479177387814f * 0.125f / 12.0f;
    long abase = (long)blockIdx.x * 32;

    // stage idx + W0 coalesced (384 ints + 384 floats = 6 x 16B x 64-lane)
    if (tid < 96)
        ((int4*)sIdx)[tid] = ((const int4*)(nbr_idx + abase * M_NBR))[tid];
    else if (tid < 192)
        ((float4*)sW)[tid - 96] = ((const float4*)(W0 + abase * M_NBR))[tid - 96];
    __syncthreads();

    int al = wv * 8 + aw;            // atom local 0..31
    int4   i0 = *(const int4*)&sIdx[al * M_NBR];
    int4   i1 = *(const int4*)&sIdx[al * M_NBR + 4];
    int4   i2 = *(const int4*)&sIdx[al * M_NBR + 8];
    float4 w0 = *(const float4*)&sW[al * M_NBR];
    float4 w1 = *(const float4*)&sW[al * M_NBR + 4];
    float4 w2 = *(const float4*)&sW[al * M_NBR + 8];

    const unsigned short* xb = x_in + oct * 8;
    float a0=0.f,a1=0.f,a2=0.f,a3=0.f,a4=0.f,a5=0.f,a6=0.f,a7=0.f;
    #define GJ(IDX, WW) { \
        uint4 v = *(const uint4*)(xb + (size_t)(IDX) * F_DIM); \
        a0 = fmaf(WW, bf2f(v.x & 0xffffu), a0); \
        a1 = fmaf(WW, bf2f(v.x >> 16),     a1); \
        a2 = fmaf(WW, bf2f(v.y & 0xffffu), a2); \
        a3 = fmaf(WW, bf2f(v.y >> 16),     a3); \
        a4 = fmaf(WW, bf2f(v.z & 0xffffu), a4); \
        a5 = fmaf(WW, bf2f(v.z >> 16),     a5); \
        a6 = fmaf(WW, bf2f(v.w & 0xffffu), a6); \
        a7 = fmaf(WW, bf2f(v.w >> 16),     a7); }
    GJ(i0.x, w0.x) GJ(i0.y, w0.y) GJ(i0.z, w0.z) GJ(i0.w, w0.w)
    GJ(i1.x, w1.x) GJ(i1.y, w1.y) GJ(i1.z, w1.z) GJ(i1.w, w1.w)
    GJ(i2.x, w2.x) GJ(i2.y, w2.y) GJ(i2.z, w2.z) GJ(i2.w, w2.w)
    #undef GJ

    short8 pk;
    pk[0] = (short)f2bf(a0 * cscale); pk[1] = (short)f2bf(a1 * cscale);
    pk[2] = (short)f2bf(a2 * cscale); pk[3] = (short)f2bf(a3 * cscale);
    pk[4] = (short)f2bf(a4 * cscale); pk[5] = (short)f2bf(a5 * cscale);
    pk[6] = (short)f2bf(a6 * cscale); pk[7] = (short)f2bf(a7 * cscale);
    int wb = (al * 128 + oct * 16) ^ ((al & 7) << 4);
    *(short8*)((char*)gl + wb) = pk;
    __syncthreads();

    // TP (swapped): D = Wtp^T . g^T.  wave -> atom-tile (wv&1), n-pair (wv>>1)
    int sub = lane & 15, quad = lane >> 4;
    int at = (wv & 1) * 16 + sub;    // atom (second-operand t-dim)
    int nb = (wv >> 1) * 2;
    short8 gfr[2];
    #pragma unroll
    for (int s = 0; s < 2; ++s) {
        int rb = (at * 128 + s * 64 + quad * 16) ^ ((at & 7) << 4);
        gfr[s] = *(const short8*)((const char*)gl + rb);
    }
    const unsigned short* bb = wtp + lane * 64;   // 128 B/lane frags
    floatx4 acc[2] = {{0.f,0.f,0.f,0.f},{0.f,0.f,0.f,0.f}};
    #pragma unroll
    for (int s = 0; s < 2; ++s)
        #pragma unroll
        for (int nti = 0; nti < 2; ++nti) {
            short8 wfr = *(const short8*)(bb + (nb + nti) * 16 + s * 8);
            acc[nti] = __builtin_amdgcn_mfma_f32_16x16x32_bf16(wfr, gfr[s], acc[nti], 0, 0, 0);
        }
    // D rows = features (nb+nti)*16+quad*4+reg, col = atom (wv&1)*16+sub
    size_t ob = ((size_t)blockIdx.x * 32 + (wv & 1) * 16 + sub) * F_DIM;
    #pragma unroll
    for (int nti = 0; nti < 2; ++nti) {
        uint2 o = { pk2(acc[nti][0], acc[nti][1]), pk2(acc[nti][2], acc[nti][3]) };
        *(uint2*)&x_out[ob + (nb + nti) * 16 + quad * 4] = o;
    }
}

// ---------------------------------------------------------------------------
// Readout v2: idx staged in LDS; coalesced uint2 row-gathers (8 row-groups x
// 16 col-threads) instead of 50 scattered u16 loads per thread.
// ---------------------------------------------------------------------------
__global__ __launch_bounds__(128) void k_readout(
    const unsigned short* __restrict__ x, const int* __restrict__ cidx,
    const float* __restrict__ W_fc, const float* __restrict__ b_fc,
    const float* __restrict__ W_out, const float* __restrict__ b_out,
    float* __restrict__ out, float* __restrict__ hout)
{
    __shared__ int sIdx[APB];
    __shared__ float4 red[8][16];
    __shared__ float crys[F_DIM];
    __shared__ float hw[HFEA];
    int tid = threadIdx.x;
    int c = blockIdx.x;
    if (tid < APB) sIdx[tid] = cidx[c * APB + tid];
    __syncthreads();
    int cq = tid & 15, rg = tid >> 4;
    float4 acc = {0.f, 0.f, 0.f, 0.f};
    for (int r = rg; r < APB; r += 8) {
        int a = sIdx[r];
        uint2 v = *(const uint2*)(x + (size_t)a * F_DIM + cq * 4);
        acc.x += bf2f(v.x & 0xffffu);
        acc.y += bf2f(v.x >> 16);
        acc.z += bf2f(v.y & 0xffffu);
        acc.w += bf2f(v.y >> 16);
    }
    red[rg][cq] = acc;
    __syncthreads();
    if (tid < 16) {
        float4 s = red[0][tid];
        #pragma unroll
        for (int g = 1; g < 8; ++g) {
            float4 r4 = red[g][tid];
            s.x += r4.x; s.y += r4.y; s.z += r4.z; s.w += r4.w;
        }
        const float inv = 1.0f / APB;
        s.x *= inv; s.y *= inv; s.z *= inv; s.w *= inv;
        *(float4*)&crys[tid * 4] = s;
    }
    __syncthreads();
    float acc2 = b_fc[tid];
    for (int ff = 0; ff < F_DIM; ++ff)
        acc2 = fmaf(crys[ff], W_fc[ff * HFEA + tid], acc2);
    float h = softplus_f(acc2);
    hout[(size_t)c * HFEA + tid] = h;
    hw[tid] = h * W_out[tid];
    __syncthreads();
    if (tid == 0) {
        float s = b_out[0];
        #pragma unroll 16
        for (int j = 0; j < HFEA; ++j) s += hw[j];
        out[c] = s;
    }
}

extern "C" void kernel_launch(void* const* d_in, const int* in_sizes, int n_in,
                              void* d_out, int out_size, void* d_ws, size_t ws_size,
                              hipStream_t stream) {
    const float* atom_fea = (const float*)d_in[0];
    const float* nbr_fea  = (const float*)d_in[1];
    const int*   nbr_idx  = (const int*)d_in[2];
    const int*   cidx     = (const int*)d_in[3];
    // d_in[4] = pos : unused (Y[:, :1] is the constant l=0 channel)
    const float* W_emb = (const float*)d_in[5];
    const float* b_emb = (const float*)d_in[6];
    const float* Wr1   = (const float*)d_in[7];
    const float* br1   = (const float*)d_in[8];
    const float* Wr2   = (const float*)d_in[9];
    const float* br2   = (const float*)d_in[10];
    const float* Wtp   = (const float*)d_in[11];
    const float* W_fc  = (const float*)d_in[12];
    const float* b_fc  = (const float*)d_in[13];
    const float* W_out = (const float*)d_in[14];
    const float* b_out = (const float*)d_in[15];

    float* out  = (float*)d_out;
    float* hout = out + B_CRYS;

    float* W0 = (float*)d_ws;                                   // 3*2.4M fp32
    unsigned short* xA = (unsigned short*)(W0 + 3 * (size_t)EDGES);
    unsigned short* xB = xA + (size_t)N_ATOMS * F_DIM;

    // Prep packs alias the START of xB (all consumed before conv#1 writes xB).
    unsigned short* wpak  = xB;                         // 9216 u16 (18 KB)
    float*          w2pk  = (float*)(wpak + 9216);      // 2304 fp32
    float*          b1pk  = w2pk + 2304;                // 2304 fp32
    unsigned short* wepak = (unsigned short*)(b1pk + 2304);  // 6144 u16 (12 KB)
    float*          bepk  = (float*)(wepak + 6144);     // 1024 fp32
    // Wtp pack must survive through conv#3 -> park in the hout scratch region
    // (k_readout fully overwrites hout afterwards).
    unsigned short* wtpak = (unsigned short*)(hout + 128000);   // 12288 u16

    k_prep  <<<1, 256, 0, stream>>>(Wr1, br1, Wr2, Wtp, W_emb, b_emb,
                                    wpak, w2pk, b1pk, wtpak, wepak, bepk);
    k_embed <<<N_ATOMS / 64, 256, 0, stream>>>(atom_fea, wepak, bepk, xA);
    k_filter<<<EDGES / 256, 256, 0, stream>>>(nbr_fea, wpak, w2pk, b1pk, br2, W0);
    k_conv  <<<N_ATOMS / 32, 256, 0, stream>>>(xA, nbr_idx, W0,             wtpak,            xB);
    k_conv  <<<N_ATOMS / 32, 256, 0, stream>>>(xB, nbr_idx, W0 + EDGES,     wtpak + 4096,     xA);
    k_conv  <<<N_ATOMS / 32, 256, 0, stream>>>(xA, nbr_idx, W0 + 2 * EDGES, wtpak + 2 * 4096, xB);
    k_readout<<<B_CRYS, 128, 0, stream>>>(xB, cidx, W_fc, b_fc, W_out, b_out, out, hout);
}